// Round 4
// baseline (277.605 us; speedup 1.0000x reference)
//
#include <hip/hip_runtime.h>

// Problem constants (HyperNetwork_9990093931021)
#define BB 256   // batch
#define CC 512   // channels
#define NZ 256   // flattened spatial (16*16)
#define ZD 64    // z_dim
#define KK 9     // out_c * f * f = 1*3*3

// ---- DPP cross-lane add helpers (VALU-only) ----
template<int CTRL>
__device__ __forceinline__ float dpp_add(float v) {
    int o = __builtin_amdgcn_update_dpp(0, __float_as_int(v), CTRL, 0xF, 0xF, true);
    return v + __int_as_float(o);
}
__device__ __forceinline__ float red8(float v) {
    v = dpp_add<0xB1>(v);   // xor 1 (quad_perm [1,0,3,2])
    v = dpp_add<0x4E>(v);   // xor 2 (quad_perm [2,3,0,1])
    v = dpp_add<0x141>(v);  // row_half_mirror (combine quads of the 8-lane half)
    return v;
}

// grid = 512 blocks (one c each; 2 blocks/CU, all resident), block = 256 (4 waves).
// Phase 1: fused weight Wf[k][n] = sum_z W_in[c,n,z]*W_out[z,k] into LDS.
// Phase 2: 8 chunks x 32 b; 8-lane group owns one full b-row per chunk,
// chunk-level register double-buffer (8 loads in flight per wave) so load
// issue never stalls on the 900-cycle HBM latency.
__global__ __launch_bounds__(256, 2)
void hyper_kernel(const float* __restrict__ z,
                  const float* __restrict__ W_in,
                  const float* __restrict__ b_in,
                  const float* __restrict__ W_out,
                  const float* __restrict__ b_out,
                  float* __restrict__ out) {
    __shared__ __align__(16) float s_wf[KK * NZ];    // fused weight [k][n], 9216 B
    __shared__ __align__(16) float s_woutT[KK * ZD]; // W_out^T [k][z]
    __shared__ float s_bin[ZD];
    __shared__ float s_bias[KK];

    const int c = blockIdx.x;
    const int t = threadIdx.x;
    const int lane = t & 63;
    const int wave = t >> 6;
    const int g = lane >> 3;
    const int sub = lane & 7;            // lane's 1/8 slice of a b-row
    const int gb = wave * 8 + g;         // group id in block (0..31)

    const size_t zrow = (size_t)CC * NZ; // b stride in z (floats)
    const float* zbase = z + (size_t)c * NZ + sub * 4;

    float4 xb0[8], xb1[8];

    // issue chunk-0 z preload FIRST: overlaps all of phase 1
    {
        const float* xp = zbase + (size_t)gb * zrow;
#pragma unroll
        for (int j = 0; j < 8; ++j)      // 8-lane group covers one 128B line per j
            xb0[j] = *reinterpret_cast<const float4*>(xp + j * 32);
    }

    // ---- phase 1 staging ----
    for (int i = t; i < KK * ZD; i += 256) {
        float v = W_out[i];                            // coalesced
        int zz = i / KK, k = i - zz * KK;
        s_woutT[k * ZD + zz] = v;
    }
    if (t < ZD) s_bin[t] = b_in[c * ZD + t];
    __syncthreads();

    // ---- phase 1 compute: thread t owns n = t ----
    {
        const float* wrow = W_in + ((size_t)c * NZ + t) * ZD;
        float acc[KK];
#pragma unroll
        for (int k = 0; k < KK; ++k) acc[k] = 0.f;
#pragma unroll
        for (int j = 0; j < 16; ++j) {
            const float4 w = *reinterpret_cast<const float4*>(wrow + 4 * j);
#pragma unroll
            for (int k = 0; k < KK; ++k) {
                const float4 wo = *reinterpret_cast<const float4*>(
                    &s_woutT[k * ZD + 4 * j]);         // all-lane broadcast
                acc[k] += w.x * wo.x + w.y * wo.y + w.z * wo.z + w.w * wo.w;
            }
        }
#pragma unroll
        for (int k = 0; k < KK; ++k) s_wf[k * NZ + t] = acc[k]; // 2-way bank alias: free
        if (t < KK) {                                   // fused bias
            float s = 0.f;
            for (int zz = 0; zz < ZD; ++zz) s += s_bin[zz] * s_woutT[t * ZD + zz];
            s_bias[t] = s + b_out[t];
        }
    }
    __syncthreads();

    const float biasS = s_bias[sub];
    const float bias8 = s_bias[8];

    auto preload = [&](float4 (&x)[8], int ci) {
        const float* xp = zbase + (size_t)(ci * 32 + gb) * zrow;
#pragma unroll
        for (int j = 0; j < 8; ++j)
            x[j] = *reinterpret_cast<const float4*>(xp + j * 32);
    };
    auto compute_store = [&](const float4 (&x)[8], int ci) {
        float a[KK];
#pragma unroll
        for (int k = 0; k < KK; ++k) a[k] = 0.f;
#pragma unroll
        for (int k = 0; k < KK; ++k) {
#pragma unroll
            for (int j = 0; j < 8; ++j) {
                const float4 wf = *reinterpret_cast<const float4*>(
                    &s_wf[k * NZ + sub * 4 + j * 32]); // 128B span, group-broadcast
                a[k] += x[j].x * wf.x + x[j].y * wf.y + x[j].z * wf.z + x[j].w * wf.w;
            }
        }
#pragma unroll
        for (int k = 0; k < KK; ++k) a[k] = red8(a[k]);
        float v = a[0];
#pragma unroll
        for (int k = 1; k < 8; ++k) {
            if (sub == k) v = a[k];                    // cndmask chain
        }
        const int b = ci * 32 + gb;
        const size_t o0 = ((size_t)b * CC + c) * KK;
        out[o0 + sub] = v + biasS;
        if (sub == 0) out[o0 + 8] = a[8] + bias8;
    };

    // ---- phase 2: chunk-level double-buffered pipeline (no barriers) ----
#pragma unroll 1
    for (int ci = 0; ci < 6; ci += 2) {
        preload(xb1, ci + 1);
        compute_store(xb0, ci);
        preload(xb0, ci + 2);
        compute_store(xb1, ci + 1);
    }
    preload(xb1, 7);
    compute_store(xb0, 6);
    compute_store(xb1, 7);
}

extern "C" void kernel_launch(void* const* d_in, const int* in_sizes, int n_in,
                              void* d_out, int out_size, void* d_ws, size_t ws_size,
                              hipStream_t stream) {
    const float* z     = (const float*)d_in[0];
    const float* W_in  = (const float*)d_in[1];
    const float* b_in  = (const float*)d_in[2];
    const float* W_out = (const float*)d_in[3];
    const float* b_out = (const float*)d_in[4];
    float* out = (float*)d_out;
    hyper_kernel<<<dim3(CC), dim3(256), 0, stream>>>(z, W_in, b_in, W_out, b_out, out);
}

// Round 5
// 229.948 us; speedup vs baseline: 1.2073x; 1.2073x over previous
//
#include <hip/hip_runtime.h>

// Problem constants (HyperNetwork_9990093931021)
#define BB 256   // batch
#define CC 512   // channels
#define NZ 256   // flattened spatial (16*16)
#define ZD 64    // z_dim
#define KK 9     // out_c * f * f = 1*3*3
#define WFSZ (KK * NZ)   // fused weight floats per channel = 2304
#define CT 4     // channels per out-tile
#define BT 64    // batch per out-tile

// ---- DPP cross-lane add helpers (VALU-only) ----
template<int CTRL>
__device__ __forceinline__ float dpp_add(float v) {
    int o = __builtin_amdgcn_update_dpp(0, __float_as_int(v), CTRL, 0xF, 0xF, true);
    return v + __int_as_float(o);
}
__device__ __forceinline__ float red8(float v) {
    v = dpp_add<0xB1>(v);   // xor 1 (quad_perm [1,0,3,2])
    v = dpp_add<0x4E>(v);   // xor 2 (quad_perm [2,3,0,1])
    v = dpp_add<0x141>(v);  // row_half_mirror (combine quads of the 8-lane half)
    return v;
}

// ---- Kernel A: fused weight + fused bias into workspace (proven in R3) ----
__global__ __launch_bounds__(512, 2)
void wf_kernel(const float* __restrict__ W_in, const float* __restrict__ b_in,
               const float* __restrict__ W_out, const float* __restrict__ b_out,
               float* __restrict__ wf, float* __restrict__ biask) {
    __shared__ __align__(16) float s_woutT[KK * ZD]; // [k][z]
    __shared__ float s_bin[ZD];
    const int c = blockIdx.x;
    const int t = threadIdx.x;

    for (int i = t; i < KK * ZD; i += 512) {
        float v = W_out[i];
        int zz = i / KK, k = i - zz * KK;
        s_woutT[k * ZD + zz] = v;
    }
    if (t < ZD) s_bin[t] = b_in[c * ZD + t];
    __syncthreads();

    const int n = t >> 1, half = t & 1;
    const float* wrow = W_in + ((size_t)c * NZ + n) * ZD + half * 32;
    float acc[KK];
#pragma unroll
    for (int k = 0; k < KK; ++k) acc[k] = 0.f;
#pragma unroll
    for (int j = 0; j < 8; ++j) {
        const float4 w = *reinterpret_cast<const float4*>(wrow + 4 * j);
#pragma unroll
        for (int k = 0; k < KK; ++k) {
            const float4 wo = *reinterpret_cast<const float4*>(
                &s_woutT[k * ZD + half * 32 + 4 * j]);
            acc[k] += w.x * wo.x + w.y * wo.y + w.z * wo.z + w.w * wo.w;
        }
    }
#pragma unroll
    for (int k = 0; k < KK; ++k) acc[k] = dpp_add<0xB1>(acc[k]);
    if (half == 0) {
#pragma unroll
        for (int k = 0; k < KK; ++k)
            wf[(size_t)c * WFSZ + k * NZ + n] = acc[k];
    }
    if (t < KK) {
        float s = 0.f;
        for (int zz = 0; zz < ZD; ++zz) s += s_bin[zz] * s_woutT[t * ZD + zz];
        biask[c * KK + t] = s + b_out[t];
    }
}

// ---- Kernel B: 4c x 64b tile per block; LDS-staged coalesced output ----
// grid = 128 c-tiles (fast) x 4 b-tiles -> 512 blocks x 8 waves = 16 waves/CU.
// The 4 blocks sharing a c-tile are blockIdx = ctile + 128*btile -> same XCD
// (round-robin %8) -> Wf tile L2-hot on re-read.
__global__ __launch_bounds__(512, 4)
void out_kernel(const float* __restrict__ z, const float* __restrict__ wf,
                const float* __restrict__ biask, float* __restrict__ out) {
    __shared__ __align__(16) float s_wf[CT * WFSZ];      // 36 KB, [c][k][n]
    __shared__ __align__(16) float s_out[BT * CT * KK];  // 9 KB, [b][c][k]
    __shared__ float s_b[CT * KK];

    const int ctile = blockIdx.x & 127;
    const int btile = blockIdx.x >> 7;
    const int c0 = ctile * CT;
    const int b0 = btile * BT;
    const int t = threadIdx.x;
    const int G64 = t >> 3;          // group id 0..63 (= wave*8 + lane/8)
    const int sub = t & 7;           // lane's 16B slice of an n-chunk
    const int c_idx = G64 & 3;       // group's channel within the quad
    const int bq = G64 >> 2;         // group's b-quad 0..15

    // ---- z preload for j=0,1 FIRST (overlaps all LDS staging latency) ----
    const size_t zrow = (size_t)CC * NZ;
    const float* zp = z + ((size_t)(b0 + bq * 4) * CC + (c0 + c_idx)) * NZ + sub * 4;
    float4 xb[3][4];                 // 3-deep j pipeline x 4 b
#pragma unroll
    for (int bb = 0; bb < 4; ++bb)
        xb[0][bb] = *reinterpret_cast<const float4*>(zp + bb * zrow);
#pragma unroll
    for (int bb = 0; bb < 4; ++bb)
        xb[1][bb] = *reinterpret_cast<const float4*>(zp + bb * zrow + 32);

    // ---- stage Wf c-quad (36 KB contiguous, L2/L3-hot) + bias ----
    {
        const float4* g4 = reinterpret_cast<const float4*>(wf + (size_t)c0 * WFSZ);
        float4* s4 = reinterpret_cast<float4*>(s_wf);
        for (int i = t; i < CT * (WFSZ / 4); i += 512) s4[i] = g4[i];
        if (t < CT * KK) s_b[t] = biask[c0 * KK + t];
    }
    __syncthreads();

    // ---- main: acc[4b][9k], stream j with 3-deep buffer ----
    float acc[4][KK];
#pragma unroll
    for (int bb = 0; bb < 4; ++bb)
#pragma unroll
        for (int k = 0; k < KK; ++k) acc[bb][k] = 0.f;

    const float* wbase = &s_wf[c_idx * WFSZ + sub * 4];

#pragma unroll
    for (int j = 0; j < 8; ++j) {
        if (j + 2 < 8) {             // prefetch j+2 into the slot freed at j-1
#pragma unroll
            for (int bb = 0; bb < 4; ++bb)
                xb[(j + 2) % 3][bb] =
                    *reinterpret_cast<const float4*>(zp + bb * zrow + (j + 2) * 32);
        }
#pragma unroll
        for (int k = 0; k < KK; ++k) {
            const float4 w = *reinterpret_cast<const float4*>(wbase + k * NZ + j * 32);
#pragma unroll
            for (int bb = 0; bb < 4; ++bb) {
                const float4 x = xb[j % 3][bb];
                acc[bb][k] += x.x * w.x + x.y * w.y + x.z * w.z + x.w * w.w;
            }
        }
    }

    // ---- reduce across the 8-lane group, fold bias, stage to LDS ----
#pragma unroll
    for (int bb = 0; bb < 4; ++bb)
#pragma unroll
        for (int k = 0; k < KK; ++k) acc[bb][k] = red8(acc[bb][k]);

    const float biasS = s_b[c_idx * KK + sub];
    const float bias8 = s_b[c_idx * KK + 8];
#pragma unroll
    for (int bb = 0; bb < 4; ++bb) {
        float v = acc[bb][0];
#pragma unroll
        for (int k = 1; k < 8; ++k) {
            if (sub == k) v = acc[bb][k];            // cndmask chain
        }
        const int bl = bq * 4 + bb;                  // b_local 0..63
        s_out[bl * (CT * KK) + c_idx * KK + sub] = v + biasS;
        if (sub == 0) s_out[bl * (CT * KK) + c_idx * KK + 8] = acc[bb][8] + bias8;
    }
    __syncthreads();

    // ---- cooperative coalesced write: per b, 36 floats = 9 aligned float4 ----
    for (int i = t; i < BT * KK; i += 512) {         // 576 float4 stores
        const int bl = i / KK, q = i - bl * KK;
        const size_t dst = ((size_t)(b0 + bl) * CC + c0) * KK + q * 4; // 144B-aligned base
        *reinterpret_cast<float4*>(&out[dst]) =
            *reinterpret_cast<const float4*>(&s_out[bl * (CT * KK) + q * 4]);
    }
}

extern "C" void kernel_launch(void* const* d_in, const int* in_sizes, int n_in,
                              void* d_out, int out_size, void* d_ws, size_t ws_size,
                              hipStream_t stream) {
    const float* z     = (const float*)d_in[0];
    const float* W_in  = (const float*)d_in[1];
    const float* b_in  = (const float*)d_in[2];
    const float* W_out = (const float*)d_in[3];
    const float* b_out = (const float*)d_in[4];
    float* out = (float*)d_out;

    float* wfbuf = (float*)d_ws;                       // CC*WFSZ floats = 4.7 MB
    float* biask = (float*)d_ws + (size_t)CC * WFSZ;   // CC*KK floats

    wf_kernel<<<dim3(CC), dim3(512), 0, stream>>>(W_in, b_in, W_out, b_out, wfbuf, biask);
    out_kernel<<<dim3(4 * 128), dim3(512), 0, stream>>>(z, wfbuf, biask, out);
}

// Round 6
// 228.828 us; speedup vs baseline: 1.2132x; 1.0049x over previous
//
#include <hip/hip_runtime.h>

// Problem constants (HyperNetwork_9990093931021)
#define BB 256   // batch
#define CC 512   // channels
#define NZ 256   // flattened spatial (16*16)
#define ZD 64    // z_dim
#define KK 9     // out_c * f * f = 1*3*3
#define WFSZ (KK * NZ)   // fused weight floats per channel = 2304
#define TR 32            // z rows per LDS tile
#define NT (BB / TR)     // 8 tiles per block

// ---- DPP cross-lane add helpers (VALU-only) ----
template<int CTRL>
__device__ __forceinline__ float dpp_add(float v) {
    int o = __builtin_amdgcn_update_dpp(0, __float_as_int(v), CTRL, 0xF, 0xF, true);
    return v + __int_as_float(o);
}
__device__ __forceinline__ float red16(float v) {   // sum over aligned 16-lane group
    v = dpp_add<0xB1>(v);    // quad_perm [1,0,3,2]  (xor 1)
    v = dpp_add<0x4E>(v);    // quad_perm [2,3,0,1]  (xor 2)
    v = dpp_add<0x141>(v);   // row_half_mirror      (combine quads within 8)
    v = dpp_add<0x140>(v);   // row_mirror           (combine 8-halves within 16)
    return v;
}

// async global->LDS, 16 B per lane, LDS dest = wave-uniform base + lane*16
__device__ __forceinline__ void gld_lds16(const float* g, float* l) {
    __builtin_amdgcn_global_load_lds(
        (const __attribute__((address_space(1))) unsigned int*)(g),
        (__attribute__((address_space(3))) unsigned int*)(l),
        16, 0, 0);
}

// ---- Kernel A: fused weight + fused bias into workspace (proven R3/R5) ----
__global__ __launch_bounds__(512, 2)
void wf_kernel(const float* __restrict__ W_in, const float* __restrict__ b_in,
               const float* __restrict__ W_out, const float* __restrict__ b_out,
               float* __restrict__ wf, float* __restrict__ biask) {
    __shared__ __align__(16) float s_woutT[KK * ZD]; // [k][z]
    __shared__ float s_bin[ZD];
    const int c = blockIdx.x;
    const int t = threadIdx.x;

    for (int i = t; i < KK * ZD; i += 512) {
        float v = W_out[i];
        int zz = i / KK, k = i - zz * KK;
        s_woutT[k * ZD + zz] = v;
    }
    if (t < ZD) s_bin[t] = b_in[c * ZD + t];
    __syncthreads();

    const int n = t >> 1, half = t & 1;
    const float* wrow = W_in + ((size_t)c * NZ + n) * ZD + half * 32;
    float acc[KK];
#pragma unroll
    for (int k = 0; k < KK; ++k) acc[k] = 0.f;
#pragma unroll
    for (int j = 0; j < 8; ++j) {
        const float4 w = *reinterpret_cast<const float4*>(wrow + 4 * j);
#pragma unroll
        for (int k = 0; k < KK; ++k) {
            const float4 wo = *reinterpret_cast<const float4*>(
                &s_woutT[k * ZD + half * 32 + 4 * j]);
            acc[k] += w.x * wo.x + w.y * wo.y + w.z * wo.z + w.w * wo.w;
        }
    }
#pragma unroll
    for (int k = 0; k < KK; ++k) acc[k] = dpp_add<0xB1>(acc[k]); // half0+half1
    if (half == 0) {
#pragma unroll
        for (int k = 0; k < KK; ++k)
            wf[(size_t)c * WFSZ + k * NZ + n] = acc[k];
    }
    if (t < KK) {
        float s = 0.f;
        for (int zz = 0; zz < ZD; ++zz) s += s_bin[zz] * s_woutT[t * ZD + zz];
        biask[c * KK + t] = s + b_out[t];
    }
}

// ---- Kernel B: streaming z through LDS via async global_load_lds ----
// grid = 512 blocks (one c each, 2 blocks/CU, all resident), block = 256 (4 waves).
// Double-buffered 32-row z tiles: one global_load_lds_dwordx4 stages one full
// contiguous 1 KB z-row; waves issue the next tile's 8 KB then compute the
// current tile from LDS. Barrier's vmcnt(0) drain is the only load wait.
__global__ __launch_bounds__(256, 2)
void out_kernel(const float* __restrict__ z, const float* __restrict__ wf,
                const float* __restrict__ biask, float* __restrict__ out) {
    __shared__ __align__(16) float s_z[2][TR * NZ];  // 2 x 32 KB
    __shared__ __align__(16) float s_wf[WFSZ];       // 9 KB, [k][n]
    __shared__ float s_b[KK];

    const int c = blockIdx.x;
    const int t = threadIdx.x;
    const int lane = t & 63;
    const int wave = t >> 6;        // 0..3
    const int g16 = lane >> 4;      // 0..3 (16-lane group)
    const int s16 = lane & 15;      // lane's 16B slice of an n-chunk

    const size_t zrow = (size_t)CC * NZ;
    const float* zc = z + (size_t)c * NZ;

    // ---- issue tile-0 DMA first (wave w stages tile rows w*8 .. w*8+7) ----
#pragma unroll
    for (int r = 0; r < 8; ++r)
        gld_lds16(zc + (size_t)(wave * 8 + r) * zrow + lane * 4,
                  &s_z[0][(wave * 8 + r) * NZ]);

    // ---- stage Wf[c] + bias via vector path (overlaps the DMA) ----
    {
        const float4* g4 = reinterpret_cast<const float4*>(wf + (size_t)c * WFSZ);
        float4* s4 = reinterpret_cast<float4*>(s_wf);
        for (int i = t; i < WFSZ / 4; i += 256) s4[i] = g4[i];
        if (t < KK) s_b[t] = biask[c * KK + t];
    }

    const int r0 = wave * 8 + g16 * 2;   // this thread-group's 2 tile-local rows

#pragma unroll 1
    for (int tl = 0; tl < NT; ++tl) {
        __syncthreads();   // vmcnt(0) drain: tile tl ready; also publishes s_wf (tl=0)
        const int cur = tl & 1;
        if (tl + 1 < NT) { // issue next tile's DMA before computing this one
            const float* g0 = zc + (size_t)((tl + 1) * TR + wave * 8) * zrow;
#pragma unroll
            for (int r = 0; r < 8; ++r)
                gld_lds16(g0 + (size_t)r * zrow + lane * 4,
                          &s_z[cur ^ 1][(wave * 8 + r) * NZ]);
        }

        // ---- compute 2 rows x 9 k from LDS ----
        float a0[KK], a1[KK];
#pragma unroll
        for (int k = 0; k < KK; ++k) { a0[k] = 0.f; a1[k] = 0.f; }
#pragma unroll
        for (int j = 0; j < 4; ++j) {   // 256 B of row per j (16 lanes x 16 B)
            const float4 x0 = *reinterpret_cast<const float4*>(
                &s_z[cur][r0 * NZ + j * 64 + s16 * 4]);
            const float4 x1 = *reinterpret_cast<const float4*>(
                &s_z[cur][(r0 + 1) * NZ + j * 64 + s16 * 4]);
#pragma unroll
            for (int k = 0; k < KK; ++k) {
                const float4 w = *reinterpret_cast<const float4*>(
                    &s_wf[k * NZ + j * 64 + s16 * 4]);  // same addr all groups: bcast
                a0[k] += x0.x * w.x + x0.y * w.y + x0.z * w.z + x0.w * w.w;
                a1[k] += x1.x * w.x + x1.y * w.y + x1.z * w.z + x1.w * w.w;
            }
        }
#pragma unroll
        for (int k = 0; k < KK; ++k) { a0[k] = red16(a0[k]); a1[k] = red16(a1[k]); }

        // lane s16 = k stores component k (k < 9)
        float v0 = a0[0], v1 = a1[0];
#pragma unroll
        for (int k = 1; k < KK; ++k) {
            if (s16 == k) { v0 = a0[k]; v1 = a1[k]; }   // cndmask chain
        }
        if (s16 < KK) {
            const float bk = s_b[s16];
            const int b = tl * TR + r0;
            const size_t o0 = ((size_t)b * CC + c) * KK;
            out[o0 + s16] = v0 + bk;                     // row r0   -> batch b
            out[o0 + (size_t)CC * KK + s16] = v1 + bk;   // row r0+1 -> batch b+1
        }
    }
}

extern "C" void kernel_launch(void* const* d_in, const int* in_sizes, int n_in,
                              void* d_out, int out_size, void* d_ws, size_t ws_size,
                              hipStream_t stream) {
    const float* z     = (const float*)d_in[0];
    const float* W_in  = (const float*)d_in[1];
    const float* b_in  = (const float*)d_in[2];
    const float* W_out = (const float*)d_in[3];
    const float* b_out = (const float*)d_in[4];
    float* out = (float*)d_out;

    float* wfbuf = (float*)d_ws;                       // CC*WFSZ floats = 4.7 MB
    float* biask = (float*)d_ws + (size_t)CC * WFSZ;   // CC*KK floats

    wf_kernel<<<dim3(CC), dim3(512), 0, stream>>>(W_in, b_in, W_out, b_out, wfbuf, biask);
    out_kernel<<<dim3(CC), dim3(256), 0, stream>>>(z, wfbuf, biask, out);
}